// Round 4
// baseline (327.257 us; speedup 1.0000x reference)
//
#include <hip/hip_runtime.h>
#include <hip/hip_bf16.h>

#define K_DIM 4096
#define N_DIM 12288
#define B_DIM 64
#define G_DIM 64          // K / 64 groups
#define R_DIM 32
#define NT_DIM 768        // N / 16 n-tiles

typedef int v4i __attribute__((ext_vector_type(4)));

__device__ __forceinline__ int pack4(const v4i a) {
    return (a.x & 255) | ((a.y & 255) << 8) | ((a.z & 255) << 16) | (a.w << 24);
}

// ---------------------------------------------------------------------------
// Kernel 1: fused quantize + lora-down partial (R6 version — unchanged,
// proven in the 297.7 us baseline).
// ---------------------------------------------------------------------------
__global__ __launch_bounds__(256) void quant_lora_kernel(
    const float* __restrict__ x, const float* __restrict__ smooth,
    const float* __restrict__ ld, char* __restrict__ xq_p,
    float* __restrict__ ascale, float* __restrict__ t_part) {
    const int b = blockIdx.x >> 4;
    const int kc = blockIdx.x & 15;
    const int tid = threadIdx.x;
    const int k = kc * 256 + tid;

    __shared__ float sx[256];
    __shared__ float red[256];

    const float xd = x[b * K_DIM + k] / smooth[k];
    sx[tid] = xd;

    // --- quant (wave == group) ---
    const int lane = tid & 63;
    float a = fabsf(xd);
    #pragma unroll
    for (int off = 32; off; off >>= 1) a = fmaxf(a, __shfl_xor(a, off));
    const float as = fmaxf(a / 7.0f, 1e-8f);
    float q = rintf(xd / as);
    q = fminf(fmaxf(q, -8.0f), 7.0f);
    const int g = kc * 4 + (tid >> 6);
    const int bt = b >> 4, b15 = b & 15;
    const int quad = lane >> 4, kin = lane & 15;
    xq_p[((((size_t)bt * G_DIM + g) * 64) + quad * 16 + b15) * 16 + kin] = (char)(int)q;
    if (lane == 0) ascale[b * G_DIM + g] = as;
    __syncthreads();

    // --- lora-down partial over this 256-k chunk ---
    const int r = tid & 31, c = tid >> 5;     // c = 0..7
    const int kb = kc * 256 + c * 32;
    float acc = 0.f;
    #pragma unroll 8
    for (int kk = 0; kk < 32; ++kk)
        acc += sx[c * 32 + kk] * ld[(size_t)(kb + kk) * R_DIM + r];
    red[tid] = acc;
    __syncthreads();
    if (tid < 32) {
        float s = 0.f;
        #pragma unroll
        for (int c2 = 0; c2 < 8; ++c2) s += red[c2 * 32 + tid];
        t_part[kc * (B_DIM * R_DIM) + b * R_DIM + tid] = s;
    }
}

// ---------------------------------------------------------------------------
// Kernel 2: main — R10: barrier-free K-loop with DIRECT per-wave int32
// weight loads + in-register pack (no repack kernel, no pw round-trip,
// no LDS weight staging).
// R9 post-mortem: repack+main = ~113 us vs R0-main 90 us — the barrier-free
// main helped (~60-70 us) but the 251 MB repack materialization tax ate the
// gain. R9's repack proved the byte mapping: lane l's MFMA B-fragment is
// exactly qw[(n0 + (l&15))*K + g*64 + (l>>4)*16 .. +16] packed int32->int8.
// So load it directly here: per g per lane, 4x dwordx4 (64 B) + 4 pack4
// (v_perm) -> bq. All 4 waves of the block load the same 4 KB/group -> L1
// (32 KB/CU) absorbs the 4x instruction redundancy; HBM stays at the
// mandatory 201 MB q_w stream, read ONCE. Zero K-loop barriers -> no
// lockstep vmcnt drain; latency hidden by 12 waves/CU TLP + unroll-2 ILP
// (unroll 2 keeps VGPR ~110 << 168 = the 3-waves/SIMD limit; R7 lesson:
// never let staging push past the occupancy cliff).
// ---------------------------------------------------------------------------
__global__ __launch_bounds__(256) void main_fused_kernel(
    const int* __restrict__ qw, const float* __restrict__ wscales,
    const v4i* __restrict__ xq_p, const float* __restrict__ ascale,
    const float* __restrict__ t_part, const float* __restrict__ lora_up,
    const float* __restrict__ bias, float* __restrict__ out) {
    __shared__ float s_ws[G_DIM * 16];      // [g][j]   4 KB
    __shared__ float s_as[G_DIM * 68];      // [g][b]  17 KB (pad 68)
    __shared__ float s_t[B_DIM * R_DIM];    // [b][r]   8 KB

    const int nt = blockIdx.x;
    const int n0 = nt * 16;
    const int tid = threadIdx.x;

    // one-time LDS stages
    for (int i = tid; i < G_DIM * 16; i += 256)
        s_ws[i] = wscales[(i >> 4) * N_DIM + n0 + (i & 15)];
    for (int i = tid; i < B_DIM * G_DIM; i += 256) {
        const int b = i >> 6, g = i & 63;
        s_as[g * 68 + b] = ascale[i];
    }
    for (int i = tid; i < B_DIM * R_DIM; i += 256) {
        float s = 0.f;
        #pragma unroll
        for (int kc = 0; kc < 16; ++kc) s += t_part[kc * (B_DIM * R_DIM) + i];
        s_t[i] = s;
    }
    __syncthreads();                        // the ONLY block barrier

    const int w = tid >> 6, lane = tid & 63;
    const int col = lane & 15, quad = lane >> 4;

    float facc[4] = {0.f, 0.f, 0.f, 0.f};
    const v4i zero = {0, 0, 0, 0};
    const v4i* xbase = xq_p + (size_t)w * G_DIM * 64 + lane;          // [w][g][lane]
    const int* bsrc = qw + (size_t)(n0 + col) * K_DIM + quad * 16;    // per-lane row

    #pragma unroll 2
    for (int g = 0; g < G_DIM; ++g) {
        const int* p = bsrc + g * 64;
        const v4i a0 = *(const v4i*)(p);
        const v4i a1 = *(const v4i*)(p + 4);
        const v4i a2 = *(const v4i*)(p + 8);
        const v4i a3 = *(const v4i*)(p + 12);
        v4i bq;
        bq.x = pack4(a0); bq.y = pack4(a1); bq.z = pack4(a2); bq.w = pack4(a3);
        const v4i xa = xbase[g * 64];
        const v4i d = __builtin_amdgcn_mfma_i32_16x16x64_i8(xa, bq, zero, 0, 0, 0);
        const float wsc = s_ws[g * 16 + col];
        const float4 as4 = *(const float4*)&s_as[g * 68 + w * 16 + quad * 4];
        facc[0] = fmaf(as4.x * wsc, (float)d[0], facc[0]);
        facc[1] = fmaf(as4.y * wsc, (float)d[1], facc[1]);
        facc[2] = fmaf(as4.z * wsc, (float)d[2], facc[2]);
        facc[3] = fmaf(as4.w * wsc, (float)d[3], facc[3]);
    }

    // ---- epilogue: bias + rank-32 lora, direct store ----
    const int n = n0 + col;
    float4 lu[8];
    {
        const float4* lp = (const float4*)(lora_up + (size_t)n * R_DIM);
        #pragma unroll
        for (int i = 0; i < 8; ++i) lu[i] = lp[i];
    }
    const float bs = bias[n];
    #pragma unroll
    for (int r = 0; r < 4; ++r) {
        const int b = w * 16 + quad * 4 + r;
        float acc = facc[r] + bs;
        #pragma unroll
        for (int r2 = 0; r2 < 8; ++r2) {
            const float4 tv = *(const float4*)&s_t[b * R_DIM + r2 * 4];
            acc += tv.x * lu[r2].x + tv.y * lu[r2].y +
                   tv.z * lu[r2].z + tv.w * lu[r2].w;
        }
        out[(size_t)b * N_DIM + n] = acc;
    }
}

// ---------------------------------------------------------------------------
extern "C" void kernel_launch(void* const* d_in, const int* in_sizes, int n_in,
                              void* d_out, int out_size, void* d_ws, size_t ws_size,
                              hipStream_t stream) {
    const float* x         = (const float*)d_in[0];
    const int*   q_w       = (const int*)d_in[1];
    const float* wscales   = (const float*)d_in[2];
    const float* lora_down = (const float*)d_in[3];
    const float* lora_up   = (const float*)d_in[4];
    const float* smooth    = (const float*)d_in[5];
    const float* bias      = (const float*)d_in[6];
    float* out = (float*)d_out;

    char*  xq     = (char*)d_ws;                            // 256 KB packed acts
    float* ascale = (float*)((char*)d_ws + 262144);         // 16 KB
    float* t_part = (float*)((char*)d_ws + 262144 + 16384); // 128 KB (16 slices)

    quant_lora_kernel<<<B_DIM * 16, 256, 0, stream>>>(x, smooth, lora_down,
                                                      xq, ascale, t_part);
    main_fused_kernel<<<NT_DIM, 256, 0, stream>>>(q_w, wscales, (const v4i*)xq,
                                                  ascale, t_part, lora_up, bias, out);
}